// Round 7
// baseline (215.807 us; speedup 1.0000x reference)
//
#include <hip/hip_runtime.h>
#include <stdint.h>

#define NNODES 4096
#define FDIM 256
#define NH 4
#define HD 64
#define MWORDS 128   // 4096/32 mask words per row
#define SCAP 512     // score cache per head (fallback recompute beyond)
#define TOTROWS (NH * NNODES)          // 16384 attn rows (16 KB each)
#define ROW4 (NNODES / 4)              // 1024 float4 per row
#define R0 6144                        // D3 fills rows [0,R0)
#define R1 14336                       // D4 fills [R0,R1); D5 fills [R1,end) + scatters [0,R1)
#define FB3 24576                      // R0*ROW4/256
#define FB4 32768                      // (R1-R0)*ROW4/256
#define FB5 8192                       // (TOTROWS-R1)*ROW4/256

typedef float f4 __attribute__((ext_vector_type(4)));

// one 16B store per thread, system-scope + non-temporal (bypass L2/LLC allocate)
__device__ __forceinline__ void fill_one_nt(f4* __restrict__ base, size_t beg, size_t end,
                                            int fid, int t)
{
    size_t i = beg + (size_t)fid * 256 + t;
    if (i < end) {
        f4 z = {0.f, 0.f, 0.f, 0.f};
        f4* p = base + i;
        asm volatile("global_store_dwordx4 %0, %1, off sc0 sc1 nt"
                     :: "v"(p), "v"(z) : "memory");
    }
}

// ---------------- merged: W transpose (blocks 0..191) + mask build (rest) ----------------
__global__ __launch_bounds__(256) void k_prep(
    const float* __restrict__ Wq, const float* __restrict__ Wk,
    const float* __restrict__ Wv, float* __restrict__ Wt,
    const int* __restrict__ ei, int E, uint32_t* __restrict__ mask)
{
    __shared__ float tile[32][33];
    int t = threadIdx.x;
    if (blockIdx.x < 192) {
        int mat = blockIdx.x >> 6;
        int within = blockIdx.x & 63;
        int c0 = (within & 7) * 32, r0 = (within >> 3) * 32;
        const float* W = mat == 0 ? Wq : (mat == 1 ? Wk : Wv);
        float* dst = Wt + (size_t)mat * FDIM * FDIM;
        int tx = t & 31, ty = t >> 5;
        for (int i = ty; i < 32; i += 8)
            tile[i][tx] = W[(size_t)(r0 + i) * FDIM + c0 + tx];
        __syncthreads();
        for (int i = ty; i < 32; i += 8)
            dst[(size_t)(c0 + i) * FDIM + r0 + tx] = tile[tx][i];
    } else {
        int e = (blockIdx.x - 192) * 256 + t;
        if (e < E) {
            int r = ei[e];
            int c = ei[E + e];
            atomicOr(&mask[(size_t)r * MWORDS + (c >> 5)], 1u << (c & 31));
        }
    }
}

// ---------------- QKV projection + fill rows [0, R0) ----------------
#define TN 16
__global__ __launch_bounds__(256) void k_qkv_fill(
    const float* __restrict__ x, const float* __restrict__ Wt,
    const float* __restrict__ bq, const float* __restrict__ bk, const float* __restrict__ bv,
    float* __restrict__ qkv, float* __restrict__ attn)
{
    int t = threadIdx.x;
    if (blockIdx.x >= 3 * (NNODES / TN)) {   // filler blocks
        fill_one_nt((f4*)attn, 0, (size_t)R0 * ROW4, blockIdx.x - 3 * (NNODES / TN), t);
        return;
    }
    int mat = blockIdx.x >> 8;               // NNODES/TN == 256 blocks per matrix
    int n0 = (blockIdx.x & 255) * TN;
    const float* W = Wt + (size_t)mat * FDIM * FDIM;   // [k][t]
    const float* bias = mat == 0 ? bq : (mat == 1 ? bk : bv);
    float* dst = qkv + (size_t)mat * NNODES * FDIM;
    __shared__ float xl[TN][FDIM + 4];
    for (int f = t; f < TN * (FDIM / 4); f += 256) {
        int n = f >> 6, c4 = f & 63;
        float4 v = ((const float4*)(x + (size_t)(n0 + n) * FDIM))[c4];
        *(float4*)&xl[n][c4 * 4] = v;
    }
    __syncthreads();
    float acc[TN];
    #pragma unroll
    for (int n = 0; n < TN; ++n) acc[n] = 0.f;
    for (int k4 = 0; k4 < FDIM / 4; ++k4) {
        float w0 = W[(size_t)(k4 * 4 + 0) * FDIM + t];
        float w1 = W[(size_t)(k4 * 4 + 1) * FDIM + t];
        float w2 = W[(size_t)(k4 * 4 + 2) * FDIM + t];
        float w3 = W[(size_t)(k4 * 4 + 3) * FDIM + t];
        #pragma unroll
        for (int n = 0; n < TN; ++n) {
            float4 xv = *(const float4*)&xl[n][k4 * 4];
            acc[n] = fmaf(w0, xv.x, acc[n]);
            acc[n] = fmaf(w1, xv.y, acc[n]);
            acc[n] = fmaf(w2, xv.z, acc[n]);
            acc[n] = fmaf(w3, xv.w, acc[n]);
        }
    }
    float bb = bias[t];
    #pragma unroll
    for (int n = 0; n < TN; ++n)
        dst[(size_t)(n0 + n) * FDIM + t] = acc[n] + bb;
}

// ---------------- sparse attention + residual + LN, + fill rows [R0, R1) ----------------
__global__ __launch_bounds__(256) void k_attn_fill(
    const float* __restrict__ qkv, const uint32_t* __restrict__ mask,
    const float* __restrict__ x, const float* __restrict__ ln_g, const float* __restrict__ ln_b,
    float* __restrict__ out, float* __restrict__ stats, float* __restrict__ attn)
{
    int t = threadIdx.x;
    if (blockIdx.x >= NNODES) {              // filler blocks
        fill_one_nt((f4*)attn, (size_t)R0 * ROW4, (size_t)R1 * ROW4, blockIdx.x - NNODES, t);
        return;
    }

    const float* Q = qkv;
    const float* K = qkv + (size_t)NNODES * FDIM;
    const float* V = qkv + 2 * (size_t)NNODES * FDIM;

    __shared__ float q_lds[FDIM];
    __shared__ uint32_t mrow[MWORDS];
    __shared__ unsigned short list[NNODES];
    __shared__ float sv[NH][SCAP];
    __shared__ float red0[NH], red1[NH];
    __shared__ int cnt_s;

    int n = blockIdx.x;
    int h = t >> 6, lane = t & 63;   // wave h handles head h

    q_lds[t] = Q[(size_t)n * FDIM + t];
    float xv = x[(size_t)n * FDIM + t];
    if (t < MWORDS) mrow[t] = mask[(size_t)n * MWORDS + t];
    __syncthreads();

    // ---- neighbor compaction (wave 0, deterministic order) ----
    if (t < 64) {
        int total = 0;
        for (int r = 0; r < 2; ++r) {
            int w = r * 64 + t;
            uint32_t bits = mrow[w];
            int c = __popc(bits);
            int scan = c;
            #pragma unroll
            for (int off = 1; off < 64; off <<= 1) {
                int u = __shfl_up(scan, off);
                if (t >= off) scan += u;
            }
            int base = total + scan - c;
            while (bits) {
                int b = __ffs(bits) - 1;
                list[base++] = (unsigned short)(w * 32 + b);
                bits &= bits - 1;
            }
            total += __shfl(scan, 63);
        }
        if (t == 0) cnt_s = total;
    }
    __syncthreads();
    int cnt = cnt_s;   // >= 1 (self-loop)

    const float4* qh = (const float4*)(q_lds + h * HD);

    // ---- pass 1: scores + online softmax stats ----
    float mi = -INFINITY, li = 0.f;
    for (int i = lane; i < cnt; i += 64) {
        int m = list[i];
        const float4* kp = (const float4*)(K + (size_t)m * FDIM + h * HD);
        float s = 0.f;
        #pragma unroll
        for (int j = 0; j < HD / 4; ++j) {
            float4 a = qh[j], b = kp[j];
            s += a.x * b.x + a.y * b.y + a.z * b.z + a.w * b.w;
        }
        s *= 0.125f;
        if (i < SCAP) sv[h][i] = s;
        float nm = fmaxf(mi, s);
        li = li * __expf(mi - nm) + __expf(s - nm);
        mi = nm;
    }
    #pragma unroll
    for (int off = 32; off; off >>= 1) {
        float mo = __shfl_xor(mi, off);
        float lo = __shfl_xor(li, off);
        float nm = fmaxf(mi, mo);
        float ea = (nm == -INFINITY) ? 0.f : __expf(mi - nm);
        float eb = (nm == -INFINITY) ? 0.f : __expf(mo - nm);
        li = li * ea + lo * eb;
        mi = nm;
    }
    float M = mi;
    float Linv = 1.f / li;
    if (lane == 0) {
        stats[((size_t)h * NNODES + n) * 2 + 0] = M;
        stats[((size_t)h * NNODES + n) * 2 + 1] = Linv;
    }

    // ---- convert cached scores to probabilities (same wave: no barrier) ----
    int cm = min(cnt, SCAP);
    for (int i = lane; i < cm; i += 64)
        sv[h][i] = __expf(sv[h][i] - M) * Linv;

    // ---- PV: lane = output dim; 4 independent accumulators ----
    const float* vb = V + (size_t)h * HD + lane;
    float o0 = 0.f, o1 = 0.f, o2 = 0.f, o3 = 0.f;
    int j = 0;
    for (; j + 3 < cm; j += 4) {
        int m0 = list[j], m1 = list[j + 1], m2 = list[j + 2], m3 = list[j + 3];
        float p0 = sv[h][j], p1 = sv[h][j + 1], p2 = sv[h][j + 2], p3 = sv[h][j + 3];
        o0 = fmaf(p0, vb[(size_t)m0 * FDIM], o0);
        o1 = fmaf(p1, vb[(size_t)m1 * FDIM], o1);
        o2 = fmaf(p2, vb[(size_t)m2 * FDIM], o2);
        o3 = fmaf(p3, vb[(size_t)m3 * FDIM], o3);
    }
    for (; j < cm; ++j)
        o0 = fmaf(sv[h][j], vb[(size_t)list[j] * FDIM], o0);
    for (; j < cnt; ++j) {  // overflow fallback (degree > SCAP): recompute score
        int m = list[j];
        const float4* kp = (const float4*)(K + (size_t)m * FDIM + h * HD);
        float s = 0.f;
        #pragma unroll
        for (int jj = 0; jj < HD / 4; ++jj) {
            float4 a = qh[jj], b = kp[jj];
            s += a.x * b.x + a.y * b.y + a.z * b.z + a.w * b.w;
        }
        o0 = fmaf(__expf(s * 0.125f - M) * Linv, vb[(size_t)m * FDIM], o0);
    }
    float o = (o0 + o1) + (o2 + o3);

    // ---- residual + LayerNorm (wave shuffle reduce, 1 barrier) ----
    float y = o + xv;
    float s1 = y, s2 = y * y;
    #pragma unroll
    for (int off = 32; off; off >>= 1) {
        s1 += __shfl_xor(s1, off);
        s2 += __shfl_xor(s2, off);
    }
    if (lane == 0) { red0[h] = s1; red1[h] = s2; }
    __syncthreads();
    float ts1 = (red0[0] + red0[1]) + (red0[2] + red0[3]);
    float ts2 = (red1[0] + red1[1]) + (red1[2] + red1[3]);
    float mu = ts1 * (1.f / 256.f);
    float var = ts2 * (1.f / 256.f) - mu * mu;
    out[(size_t)n * FDIM + t] = (y - mu) * rsqrtf(var + 1e-5f) * ln_g[t] + ln_b[t];
}

// ---------------- scatter rows [rowLo,rowHi) + optional fill [fillBeg,fillEnd) ----------------
__global__ __launch_bounds__(256) void k_scatter_fill(
    const int* __restrict__ ei, int E, int nsb,
    const float* __restrict__ qkv, const float* __restrict__ stats,
    float* __restrict__ attn, int rowLo, int rowHi,
    unsigned long long fillBeg, unsigned long long fillEnd)
{
    int t = threadIdx.x;
    if (blockIdx.x >= nsb) {                 // filler blocks
        fill_one_nt((f4*)attn, (size_t)fillBeg, (size_t)fillEnd, blockIdx.x - nsb, t);
        return;
    }
    int idx = blockIdx.x * 256 + t;
    if (idx >= E * NH) return;
    int e = idx >> 2;
    int h = idx & 3;          // 4 consecutive threads share one edge -> coalesced row reads
    int r = ei[e];
    int c = ei[E + e];
    int row = h * NNODES + r;
    if (row < rowLo || row >= rowHi) return;

    const float* Q = qkv;
    const float* K = qkv + (size_t)NNODES * FDIM;
    const float4* qp = (const float4*)(Q + (size_t)r * FDIM + h * HD);
    const float4* kp = (const float4*)(K + (size_t)c * FDIM + h * HD);
    float s = 0.f;
    #pragma unroll
    for (int j = 0; j < HD / 4; ++j) {
        float4 a = qp[j], b = kp[j];
        s += a.x * b.x + a.y * b.y + a.z * b.z + a.w * b.w;
    }
    float M = stats[(size_t)row * 2 + 0];
    float Linv = stats[(size_t)row * 2 + 1];
    // duplicates in the edge list write the same value -> benign race
    attn[(size_t)row * NNODES + c] = __expf(s * 0.125f - M) * Linv;
}

extern "C" void kernel_launch(void* const* d_in, const int* in_sizes, int n_in,
                              void* d_out, int out_size, void* d_ws, size_t ws_size,
                              hipStream_t stream)
{
    const float* x    = (const float*)d_in[0];
    const int*   ei   = (const int*)d_in[1];
    const float* Wq   = (const float*)d_in[2];
    const float* bq   = (const float*)d_in[3];
    const float* Wk   = (const float*)d_in[4];
    const float* bk   = (const float*)d_in[5];
    const float* Wv   = (const float*)d_in[6];
    const float* bv   = (const float*)d_in[7];
    const float* ln_g = (const float*)d_in[8];
    const float* ln_b = (const float*)d_in[9];
    float* out = (float*)d_out;
    float* attn = out + (size_t)NNODES * FDIM;

    int E = in_sizes[1] / 2;

    // ws layout (floats): Wt[3*256*256] | QKV[3*4096*256] | mask[4096*128 u32] | stats[4*4096*2]
    float* Wt  = (float*)d_ws;
    float* qkv = Wt + 3 * FDIM * FDIM;
    uint32_t* mask = (uint32_t*)(qkv + 3 * (size_t)NNODES * FDIM);
    float* stats = (float*)(mask + (size_t)NNODES * MWORDS);

    hipMemsetAsync(mask, 0, (size_t)NNODES * MWORDS * sizeof(uint32_t), stream);

    // D2: transpose (192 blocks) + mask build
    int nbuild = (E + 255) / 256;
    k_prep<<<192 + nbuild, 256, 0, stream>>>(Wq, Wk, Wv, Wt, ei, E, mask);

    // D3: qkv (768 blocks) + fill rows [0, R0)
    k_qkv_fill<<<3 * (NNODES / TN) + FB3, 256, 0, stream>>>(x, Wt, bq, bk, bv, qkv, attn);

    // D4: attn stats/out (4096 blocks) + fill rows [R0, R1)
    k_attn_fill<<<NNODES + FB4, 256, 0, stream>>>(qkv, mask, x, ln_g, ln_b, out, stats, attn);

    // D5: scatter rows [0, R1) + fill rows [R1, 16384)
    int nsb = (E * NH + 255) / 256;
    k_scatter_fill<<<nsb + FB5, 256, 0, stream>>>(
        ei, E, nsb, qkv, stats, attn, 0, R1,
        (unsigned long long)R1 * ROW4, (unsigned long long)TOTROWS * ROW4);

    // D6: scatter tail rows [R1, 16384)
    k_scatter_fill<<<nsb, 256, 0, stream>>>(
        ei, E, nsb, qkv, stats, attn, R1, TOTROWS, 0ull, 0ull);
}

// Round 8
// 195.053 us; speedup vs baseline: 1.1064x; 1.1064x over previous
//
#include <hip/hip_runtime.h>
#include <stdint.h>

#define NNODES 4096
#define FDIM 256
#define NH 4
#define HD 64
#define MWORDS 128   // 4096/32 mask words per row
#define SCAP 512     // score cache per head (fallback recompute beyond)
#define TOTROWS (NH * NNODES)          // 16384 attn rows (16 KB each)
#define ROW4 (NNODES / 4)              // 1024 float4 per row
// fill split (rows): D2 [0,S0) | D3 [S0,S1) | D4 [S1,RTAIL) | D5 merged-fill [RTAIL,end)
#define S0 1024
#define S1 7936
#define RTAIL 14848
#define FB2 ((S0) * 4)                 // 4096  filler blocks in D2 (1 row = 4 blocks)
#define FB3 ((S1 - S0) * 4)            // 27648 filler blocks in D3
#define FB4 ((RTAIL - S1) * 4)         // 27648 filler blocks in D4
#define FB5 ((TOTROWS - RTAIL) * 4)    // 6144  merged-fill blocks in D5

typedef float f4 __attribute__((ext_vector_type(4)));

// one plain 16B store per thread (best measured variant for d_out region)
__device__ __forceinline__ void fill_one(f4* __restrict__ base, size_t beg, size_t end,
                                         int fid, int t)
{
    f4 z = {0.f, 0.f, 0.f, 0.f};
    size_t i = beg + (size_t)fid * 256 + t;
    if (i < end) base[i] = z;
}

// ---------------- D2: W transpose + mask build + fill rows [0,S0) ----------------
__global__ __launch_bounds__(256) void k_prep(
    const float* __restrict__ Wq, const float* __restrict__ Wk,
    const float* __restrict__ Wv, float* __restrict__ Wt,
    const int* __restrict__ ei, int E, uint32_t* __restrict__ mask,
    float* __restrict__ attn, int nbuild)
{
    __shared__ float tile[32][33];
    int t = threadIdx.x;
    if (blockIdx.x < 192) {
        int mat = blockIdx.x >> 6;
        int within = blockIdx.x & 63;
        int c0 = (within & 7) * 32, r0 = (within >> 3) * 32;
        const float* W = mat == 0 ? Wq : (mat == 1 ? Wk : Wv);
        float* dst = Wt + (size_t)mat * FDIM * FDIM;
        int tx = t & 31, ty = t >> 5;
        for (int i = ty; i < 32; i += 8)
            tile[i][tx] = W[(size_t)(r0 + i) * FDIM + c0 + tx];
        __syncthreads();
        for (int i = ty; i < 32; i += 8)
            dst[(size_t)(c0 + i) * FDIM + r0 + tx] = tile[tx][i];
    } else if (blockIdx.x < 192 + nbuild) {
        int e = (blockIdx.x - 192) * 256 + t;
        if (e < E) {
            int r = ei[e];
            int c = ei[E + e];
            atomicOr(&mask[(size_t)r * MWORDS + (c >> 5)], 1u << (c & 31));
        }
    } else {
        fill_one((f4*)attn, 0, (size_t)S0 * ROW4, blockIdx.x - 192 - nbuild, t);
    }
}

// ---------------- D3: QKV projection + fill rows [S0, S1) ----------------
#define TN 16
__global__ __launch_bounds__(256) void k_qkv_fill(
    const float* __restrict__ x, const float* __restrict__ Wt,
    const float* __restrict__ bq, const float* __restrict__ bk, const float* __restrict__ bv,
    float* __restrict__ qkv, float* __restrict__ attn)
{
    int t = threadIdx.x;
    if (blockIdx.x >= 3 * (NNODES / TN)) {   // filler blocks
        fill_one((f4*)attn, (size_t)S0 * ROW4, (size_t)S1 * ROW4,
                 blockIdx.x - 3 * (NNODES / TN), t);
        return;
    }
    int mat = blockIdx.x >> 8;               // NNODES/TN == 256 blocks per matrix
    int n0 = (blockIdx.x & 255) * TN;
    const float* W = Wt + (size_t)mat * FDIM * FDIM;   // [k][t]
    const float* bias = mat == 0 ? bq : (mat == 1 ? bk : bv);
    float* dst = qkv + (size_t)mat * NNODES * FDIM;
    __shared__ float xl[TN][FDIM + 4];
    for (int f = t; f < TN * (FDIM / 4); f += 256) {
        int n = f >> 6, c4 = f & 63;
        float4 v = ((const float4*)(x + (size_t)(n0 + n) * FDIM))[c4];
        *(float4*)&xl[n][c4 * 4] = v;
    }
    __syncthreads();
    float acc[TN];
    #pragma unroll
    for (int n = 0; n < TN; ++n) acc[n] = 0.f;
    for (int k4 = 0; k4 < FDIM / 4; ++k4) {
        float w0 = W[(size_t)(k4 * 4 + 0) * FDIM + t];
        float w1 = W[(size_t)(k4 * 4 + 1) * FDIM + t];
        float w2 = W[(size_t)(k4 * 4 + 2) * FDIM + t];
        float w3 = W[(size_t)(k4 * 4 + 3) * FDIM + t];
        #pragma unroll
        for (int n = 0; n < TN; ++n) {
            float4 xv = *(const float4*)&xl[n][k4 * 4];
            acc[n] = fmaf(w0, xv.x, acc[n]);
            acc[n] = fmaf(w1, xv.y, acc[n]);
            acc[n] = fmaf(w2, xv.z, acc[n]);
            acc[n] = fmaf(w3, xv.w, acc[n]);
        }
    }
    float bb = bias[t];
    #pragma unroll
    for (int n = 0; n < TN; ++n)
        dst[(size_t)(n0 + n) * FDIM + t] = acc[n] + bb;
}

// ---------------- D4: sparse attention + residual + LN, + fill rows [S1, RTAIL) ----------------
__global__ __launch_bounds__(256) void k_attn_fill(
    const float* __restrict__ qkv, const uint32_t* __restrict__ mask,
    const float* __restrict__ x, const float* __restrict__ ln_g, const float* __restrict__ ln_b,
    float* __restrict__ out, float* __restrict__ stats, float* __restrict__ attn)
{
    int t = threadIdx.x;
    if (blockIdx.x >= NNODES) {              // filler blocks
        fill_one((f4*)attn, (size_t)S1 * ROW4, (size_t)RTAIL * ROW4, blockIdx.x - NNODES, t);
        return;
    }

    const float* Q = qkv;
    const float* K = qkv + (size_t)NNODES * FDIM;
    const float* V = qkv + 2 * (size_t)NNODES * FDIM;

    __shared__ float q_lds[FDIM];
    __shared__ uint32_t mrow[MWORDS];
    __shared__ unsigned short list[NNODES];
    __shared__ float sv[NH][SCAP];
    __shared__ float red0[NH], red1[NH];
    __shared__ int cnt_s;

    int n = blockIdx.x;
    int h = t >> 6, lane = t & 63;   // wave h handles head h

    q_lds[t] = Q[(size_t)n * FDIM + t];
    float xv = x[(size_t)n * FDIM + t];
    if (t < MWORDS) mrow[t] = mask[(size_t)n * MWORDS + t];
    __syncthreads();

    // ---- neighbor compaction (wave 0, deterministic order) ----
    if (t < 64) {
        int total = 0;
        for (int r = 0; r < 2; ++r) {
            int w = r * 64 + t;
            uint32_t bits = mrow[w];
            int c = __popc(bits);
            int scan = c;
            #pragma unroll
            for (int off = 1; off < 64; off <<= 1) {
                int u = __shfl_up(scan, off);
                if (t >= off) scan += u;
            }
            int base = total + scan - c;
            while (bits) {
                int b = __ffs(bits) - 1;
                list[base++] = (unsigned short)(w * 32 + b);
                bits &= bits - 1;
            }
            total += __shfl(scan, 63);
        }
        if (t == 0) cnt_s = total;
    }
    __syncthreads();
    int cnt = cnt_s;   // >= 1 (self-loop)

    const float4* qh = (const float4*)(q_lds + h * HD);

    // ---- pass 1: scores + online softmax stats ----
    float mi = -INFINITY, li = 0.f;
    for (int i = lane; i < cnt; i += 64) {
        int m = list[i];
        const float4* kp = (const float4*)(K + (size_t)m * FDIM + h * HD);
        float s = 0.f;
        #pragma unroll
        for (int j = 0; j < HD / 4; ++j) {
            float4 a = qh[j], b = kp[j];
            s += a.x * b.x + a.y * b.y + a.z * b.z + a.w * b.w;
        }
        s *= 0.125f;
        if (i < SCAP) sv[h][i] = s;
        float nm = fmaxf(mi, s);
        li = li * __expf(mi - nm) + __expf(s - nm);
        mi = nm;
    }
    #pragma unroll
    for (int off = 32; off; off >>= 1) {
        float mo = __shfl_xor(mi, off);
        float lo = __shfl_xor(li, off);
        float nm = fmaxf(mi, mo);
        float ea = (nm == -INFINITY) ? 0.f : __expf(mi - nm);
        float eb = (nm == -INFINITY) ? 0.f : __expf(mo - nm);
        li = li * ea + lo * eb;
        mi = nm;
    }
    float M = mi;
    float Linv = 1.f / li;
    if (lane == 0) {
        stats[((size_t)h * NNODES + n) * 2 + 0] = M;
        stats[((size_t)h * NNODES + n) * 2 + 1] = Linv;
    }

    // ---- convert cached scores to probabilities (same wave: no barrier) ----
    int cm = min(cnt, SCAP);
    for (int i = lane; i < cm; i += 64)
        sv[h][i] = __expf(sv[h][i] - M) * Linv;

    // ---- PV: lane = output dim; 4 independent accumulators ----
    const float* vb = V + (size_t)h * HD + lane;
    float o0 = 0.f, o1 = 0.f, o2 = 0.f, o3 = 0.f;
    int j = 0;
    for (; j + 3 < cm; j += 4) {
        int m0 = list[j], m1 = list[j + 1], m2 = list[j + 2], m3 = list[j + 3];
        float p0 = sv[h][j], p1 = sv[h][j + 1], p2 = sv[h][j + 2], p3 = sv[h][j + 3];
        o0 = fmaf(p0, vb[(size_t)m0 * FDIM], o0);
        o1 = fmaf(p1, vb[(size_t)m1 * FDIM], o1);
        o2 = fmaf(p2, vb[(size_t)m2 * FDIM], o2);
        o3 = fmaf(p3, vb[(size_t)m3 * FDIM], o3);
    }
    for (; j < cm; ++j)
        o0 = fmaf(sv[h][j], vb[(size_t)list[j] * FDIM], o0);
    for (; j < cnt; ++j) {  // overflow fallback (degree > SCAP): recompute score
        int m = list[j];
        const float4* kp = (const float4*)(K + (size_t)m * FDIM + h * HD);
        float s = 0.f;
        #pragma unroll
        for (int jj = 0; jj < HD / 4; ++jj) {
            float4 a = qh[jj], b = kp[jj];
            s += a.x * b.x + a.y * b.y + a.z * b.z + a.w * b.w;
        }
        o0 = fmaf(__expf(s * 0.125f - M) * Linv, vb[(size_t)m * FDIM], o0);
    }
    float o = (o0 + o1) + (o2 + o3);

    // ---- residual + LayerNorm (wave shuffle reduce, 1 barrier) ----
    float y = o + xv;
    float s1 = y, s2 = y * y;
    #pragma unroll
    for (int off = 32; off; off >>= 1) {
        s1 += __shfl_xor(s1, off);
        s2 += __shfl_xor(s2, off);
    }
    if (lane == 0) { red0[h] = s1; red1[h] = s2; }
    __syncthreads();
    float ts1 = (red0[0] + red0[1]) + (red0[2] + red0[3]);
    float ts2 = (red1[0] + red1[1]) + (red1[2] + red1[3]);
    float mu = ts1 * (1.f / 256.f);
    float var = ts2 * (1.f / 256.f) - mu * mu;
    out[(size_t)n * FDIM + t] = (y - mu) * rsqrtf(var + 1e-5f) * ln_g[t] + ln_b[t];
}

// ---------------- D5: scatter rows [0,RTAIL) + merged value-fill rows [RTAIL,end) ----------------
__global__ __launch_bounds__(256) void k_scatter_tailfill(
    const int* __restrict__ ei, int E, int nsb,
    const float* __restrict__ qkv, const float* __restrict__ stats,
    const uint32_t* __restrict__ mask, float* __restrict__ attn)
{
    int t = threadIdx.x;
    const float* Q = qkv;
    const float* K = qkv + (size_t)NNODES * FDIM;

    if (blockIdx.x >= nsb) {
        // merged fill-with-values: block covers 1024 cols of one tail row
        int f = blockIdx.x - nsb;               // [0, FB5)
        int row = RTAIL + (f >> 2);
        int q = f & 3;
        int h = row >> 12, n = row & 4095;
        __shared__ float qh[HD];
        __shared__ uint32_t mw[32];
        __shared__ float Ms, Ls;
        if (t < HD) qh[t] = Q[(size_t)n * FDIM + h * HD + t];
        else if (t < HD + 32) mw[t - HD] = mask[(size_t)n * MWORDS + q * 32 + (t - HD)];
        else if (t == HD + 32) { Ms = stats[(size_t)row * 2]; Ls = stats[(size_t)row * 2 + 1]; }
        __syncthreads();
        int c0 = t * 4;                          // col offset within the 1024-col window
        uint32_t nib = (mw[c0 >> 5] >> (c0 & 31)) & 0xFu;
        f4 v = {0.f, 0.f, 0.f, 0.f};
        if (nib) {
            float M = Ms, Linv = Ls;
            int cbase = q * 1024 + c0;
            #pragma unroll
            for (int j = 0; j < 4; ++j) {
                if ((nib >> j) & 1u) {
                    const float4* kp = (const float4*)(K + (size_t)(cbase + j) * FDIM + h * HD);
                    float s = 0.f;
                    #pragma unroll
                    for (int q4 = 0; q4 < HD / 4; ++q4) {
                        float4 a = *(const float4*)&qh[q4 * 4];
                        float4 b = kp[q4];
                        s += a.x * b.x + a.y * b.y + a.z * b.z + a.w * b.w;
                    }
                    v[j] = __expf(s * 0.125f - M) * Linv;
                }
            }
        }
        *(f4*)(attn + (size_t)row * NNODES + q * 1024 + c0) = v;
        return;
    }

    int idx = blockIdx.x * 256 + t;
    if (idx >= E * NH) return;
    int e = idx >> 2;
    int h = idx & 3;          // 4 consecutive threads share one edge -> coalesced row reads
    int r = ei[e];
    int c = ei[E + e];
    int row = h * NNODES + r;
    if (row >= RTAIL) return;  // tail rows handled by merged fill

    const float4* qp = (const float4*)(Q + (size_t)r * FDIM + h * HD);
    const float4* kp = (const float4*)(K + (size_t)c * FDIM + h * HD);
    float s = 0.f;
    #pragma unroll
    for (int j = 0; j < HD / 4; ++j) {
        float4 a = qp[j], b = kp[j];
        s += a.x * b.x + a.y * b.y + a.z * b.z + a.w * b.w;
    }
    float M = stats[(size_t)row * 2 + 0];
    float Linv = stats[(size_t)row * 2 + 1];
    // duplicates in the edge list write the same value -> benign race
    attn[(size_t)row * NNODES + c] = __expf(s * 0.125f - M) * Linv;
}

extern "C" void kernel_launch(void* const* d_in, const int* in_sizes, int n_in,
                              void* d_out, int out_size, void* d_ws, size_t ws_size,
                              hipStream_t stream)
{
    const float* x    = (const float*)d_in[0];
    const int*   ei   = (const int*)d_in[1];
    const float* Wq   = (const float*)d_in[2];
    const float* bq   = (const float*)d_in[3];
    const float* Wk   = (const float*)d_in[4];
    const float* bk   = (const float*)d_in[5];
    const float* Wv   = (const float*)d_in[6];
    const float* bv   = (const float*)d_in[7];
    const float* ln_g = (const float*)d_in[8];
    const float* ln_b = (const float*)d_in[9];
    float* out = (float*)d_out;
    float* attn = out + (size_t)NNODES * FDIM;

    int E = in_sizes[1] / 2;

    // ws layout (floats): Wt[3*256*256] | QKV[3*4096*256] | mask[4096*128 u32] | stats[4*4096*2]
    float* Wt  = (float*)d_ws;
    float* qkv = Wt + 3 * FDIM * FDIM;
    uint32_t* mask = (uint32_t*)(qkv + 3 * (size_t)NNODES * FDIM);
    float* stats = (float*)(mask + (size_t)NNODES * MWORDS);

    hipMemsetAsync(mask, 0, (size_t)NNODES * MWORDS * sizeof(uint32_t), stream);

    // D2: transpose (192) + mask build + fill rows [0, S0)
    int nbuild = (E + 255) / 256;
    k_prep<<<192 + nbuild + FB2, 256, 0, stream>>>(Wq, Wk, Wv, Wt, ei, E, mask, attn, nbuild);

    // D3: qkv (768 blocks) + fill rows [S0, S1)
    k_qkv_fill<<<3 * (NNODES / TN) + FB3, 256, 0, stream>>>(x, Wt, bq, bk, bv, qkv, attn);

    // D4: attn stats/out (4096 blocks) + fill rows [S1, RTAIL)
    k_attn_fill<<<NNODES + FB4, 256, 0, stream>>>(qkv, mask, x, ln_g, ln_b, out, stats, attn);

    // D5: scatter rows [0, RTAIL) + merged value-fill rows [RTAIL, 16384)
    int nsb = (E * NH + 255) / 256;
    k_scatter_tailfill<<<nsb + FB5, 256, 0, stream>>>(ei, E, nsb, qkv, stats, mask, attn);
}